// Round 8
// baseline (216.455 us; speedup 1.0000x reference)
//
#include <hip/hip_runtime.h>
#include <hip/hip_bf16.h>

typedef __attribute__((ext_vector_type(8))) _Float16 f16x8;  // 8 fp16 (4 VGPR)
typedef __attribute__((ext_vector_type(4))) float f32x4;     // MFMA C/D frag

constexpr int Sc  = 2048;
constexpr int Dc  = 1024;
constexpr int Hc  = 16;
constexpr int HDc = 64;
constexpr int Mc  = 4096;  // B*S

constexpr float ECs = 0.18033688011112042f;  // log2(e)/8, folded into Q

__device__ __forceinline__ ushort f2h(float f) {
  return __builtin_bit_cast(ushort, (_Float16)f);
}

union US8 {
  ushort u[8];
  uint   w[4];
  f16x8  v;
};

// ---------------------------------------------------------------------------
// prep: merged split_x (blocks 0..4095) + split_wt (blocks 4096..5119).
// ---------------------------------------------------------------------------
struct SplitP {
  const float* W[4];
  ushort*      Th[4];
};

__global__ __launch_bounds__(256) void prep_kernel(
    const float* __restrict__ X, ushort* __restrict__ Xh, SplitP p) {
  __shared__ float T[64][69];
  const int wid = blockIdx.x;
  const int t   = threadIdx.x;
  if (wid < 4096) {
    const int i    = wid * 256 + t;
    const float4 v = ((const float4*)X)[i];
    ushort4 h;
    h.x = f2h(v.x);
    h.y = f2h(v.y);
    h.z = f2h(v.z);
    h.w = f2h(v.w);
    ((ushort4*)Xh)[i] = h;
    return;
  }
  const int w2 = wid - 4096;
  const int z  = w2 >> 8;
  const int by = (w2 >> 4) & 15;
  const int bx = w2 & 15;
  const float* W = p.W[z];
  const int c  = (t & 15) * 4;
  const int r  = t >> 4;
  const int n0 = bx * 64, k0 = by * 64;
#pragma unroll
  for (int pp = 0; pp < 4; ++pp) {
    const int k    = r + pp * 16;
    const float4 v = *(const float4*)(W + (size_t)(k0 + k) * 1024 + n0 + c);
    T[k][c + 0] = v.x;
    T[k][c + 1] = v.y;
    T[k][c + 2] = v.z;
    T[k][c + 3] = v.w;
  }
  __syncthreads();
#pragma unroll
  for (int pp = 0; pp < 4; ++pp) {
    const int n = r + pp * 16;
    ushort4 h;
    h.x = f2h(T[c + 0][n]);
    h.y = f2h(T[c + 1][n]);
    h.z = f2h(T[c + 2][n]);
    h.w = f2h(T[c + 3][n]);
    *(ushort4*)(p.Th[z] + (size_t)(n0 + n) * 1024 + k0 + c) = h;
  }
}

// ---------------------------------------------------------------------------
// fp16 MFMA GEMM with register-prefetch pipeline + XOR-swizzled LDS.
// ---------------------------------------------------------------------------
struct GemmP {
  const ushort* Bh[3];
  const float*  bias[3];
  void*         Out[3];
};

template <bool QKV>
__global__ __launch_bounds__(256) void gemm_f16(
    const ushort* __restrict__ A, GemmP p) {
  __shared__ __align__(16) ushort As[128 * 32];
  __shared__ __align__(16) ushort Bs[128 * 32];

  const int t  = threadIdx.x;
  const int z  = blockIdx.z;
  const int m0 = blockIdx.x * 128, n0 = blockIdx.y * 128;
  const ushort* Bh  = p.Bh[z];
  const float* bias = p.bias[z];

  const int lane = t & 63, wave = t >> 6;
  const int wm = (wave & 1) * 64, wn = (wave >> 1) * 64;

  f32x4 acc[4][4];
#pragma unroll
  for (int i = 0; i < 4; ++i)
#pragma unroll
    for (int j = 0; j < 4; ++j) acc[i][j] = (f32x4){0.f, 0.f, 0.f, 0.f};

  const int am = t >> 2;
  const int ac = t & 3;
  const ushort* gA  = A  + (size_t)(m0 + am) * 1024 + ac * 8;
  const ushort* gBh = Bh + (size_t)(n0 + am) * 1024 + ac * 8;
  const int sw = ((ac + (am >> 1)) & 3) * 8;
  const int l0 = am * 32 + sw, l1 = (am + 64) * 32 + sw;

  const int fr  = lane & 15;
  const int fkb = (((lane >> 4) + (fr >> 1)) & 3) * 16;

  f16x8 rA0, rA1, rH0, rH1;
  rA0 = *(const f16x8*)(gA);
  rA1 = *(const f16x8*)(gA + 64 * 1024);
  rH0 = *(const f16x8*)(gBh);
  rH1 = *(const f16x8*)(gBh + 64 * 1024);

  for (int k0 = 0; k0 < 1024; k0 += 32) {
    __syncthreads();
    *(f16x8*)&As[l0] = rA0;
    *(f16x8*)&As[l1] = rA1;
    *(f16x8*)&Bs[l0] = rH0;
    *(f16x8*)&Bs[l1] = rH1;
    __syncthreads();

    if (k0 + 32 < 1024) {
      const int kn = k0 + 32;
      rA0 = *(const f16x8*)(gA + kn);
      rA1 = *(const f16x8*)(gA + kn + 64 * 1024);
      rH0 = *(const f16x8*)(gBh + kn);
      rH1 = *(const f16x8*)(gBh + kn + 64 * 1024);
    }

    f16x8 a[4], b_h[4];
#pragma unroll
    for (int i = 0; i < 4; ++i) {
      const int ra = (wm + i * 16 + fr) * 64 + fkb;
      const int rb = (wn + i * 16 + fr) * 64 + fkb;
      a[i]   = *(const f16x8*)((const char*)As + ra);
      b_h[i] = *(const f16x8*)((const char*)Bs + rb);
    }
#pragma unroll
    for (int i = 0; i < 4; ++i)
#pragma unroll
      for (int j = 0; j < 4; ++j)
        acc[i][j] = __builtin_amdgcn_mfma_f32_16x16x32_f16(a[i], b_h[j], acc[i][j], 0, 0, 0);
  }

  const float osc = (QKV && z == 0) ? ECs : 1.0f;
  const int cr = (lane >> 4) * 4;
  const int cc = lane & 15;
#pragma unroll
  for (int j = 0; j < 4; ++j) {
    const int n    = n0 + wn + j * 16 + cc;
    const float bv = bias[n];
#pragma unroll
    for (int i = 0; i < 4; ++i) {
      const int mb = m0 + wm + i * 16 + cr;
#pragma unroll
      for (int r = 0; r < 4; ++r) {
        const int m   = mb + r;
        const float v = (acc[i][j][r] + bv) * osc;
        if (QKV) {
          const int b = m >> 11, s = m & 2047, h = n >> 6, hd = n & 63;
          ((ushort*)p.Out[z])[(((size_t)(b * Hc + h) * Sc + s) << 6) + hd] = f2h(v);
        } else {
          ((float*)p.Out[z])[(size_t)m * 1024 + n] = v;
        }
      }
    }
  }
}

// ---------------------------------------------------------------------------
// MFMA flash attention — QBLOCK=256, ILP-fused q-halves.
// r7 evidence: 1 wave/SIMD (occupancy 9.6%), VALUBusy halved but dur -7% ->
// latency of the serial per-wave chain is the binding constraint, and the
// s_setprio fences + duplicated LDS reads serialized the two independent
// q-half pipelines. This round: (a) QK reads each K fragment ONCE feeding 4
// independent MFMAs (2 qh x 2 mt); PV reads each V fragment ONCE for 4
// MFMAs -> LDS reads 32->16/kt and 16 independent accumulator chains keep
// the matrix pipe fed; (b) no setprio (nothing to arbitrate at 1 wave/SIMD;
// frees the scheduler); (c) launch_bounds(256,1) frees VGPR (block-count
// limits occupancy anyway). Per-chain numerics bit-identical to r7.
// ---------------------------------------------------------------------------
__global__ __launch_bounds__(256, 1) void attn_mfma3(
    const ushort* __restrict__ Q, const ushort* __restrict__ K,
    const ushort* __restrict__ V, ushort* __restrict__ CTX) {
  __shared__ __align__(16) ushort Ks[64 * 64];
  __shared__ __align__(16) ushort Vt[64 * 64];  // [d][l(k) swizzled]

  const int t    = threadIdx.x;
  const int lane = t & 63, wave = t >> 6;
  const int c16 = lane & 15, quad = lane >> 4;
  const int wg = blockIdx.x;
  const int bh = wg & 31, qt = wg >> 5;  // bh fast: xcd = bh%8 (L2 affinity)
  const int bb = bh >> 4, hh = bh & 15;

  const ushort* Qb = Q + (size_t)bh * Sc * HDc + (size_t)qt * 256 * HDc;
  const ushort* Kb = K + (size_t)bh * Sc * HDc;
  const ushort* Vb = V + (size_t)bh * Sc * HDc;

  // 64 q-rows per wave: [qh][mt][c]
  f16x8 aq[2][2][2];
#pragma unroll
  for (int qh = 0; qh < 2; ++qh)
#pragma unroll
    for (int mt = 0; mt < 2; ++mt)
#pragma unroll
      for (int c = 0; c < 2; ++c)
        aq[qh][mt][c] = *(const f16x8*)(Qb +
            (size_t)(wave * 64 + qh * 32 + mt * 16 + c16) * 64 + c * 32 + quad * 8);

  US8 ones_u;
#pragma unroll
  for (int e = 0; e < 8; ++e) ones_u.u[e] = 0x3C00;  // fp16 1.0
  const f16x8 ones = ones_u.v;
  const f32x4 kZ = (f32x4){0.f, 0.f, 0.f, 0.f};  // hoisted MFMA C=0

  f32x4 ctx[2][2][4], lacc[2][2];
#pragma unroll
  for (int qh = 0; qh < 2; ++qh)
#pragma unroll
    for (int mt = 0; mt < 2; ++mt) {
      lacc[qh][mt] = (f32x4){0.f, 0.f, 0.f, 0.f};
#pragma unroll
      for (int j = 0; j < 4; ++j) ctx[qh][mt][j] = (f32x4){0.f, 0.f, 0.f, 0.f};
    }

  const int fslot = ((quad + (c16 >> 1)) & 3) * 8;

  const int krow = t >> 2, kac = t & 3;
  const int kl = krow * 64 + ((kac + (krow >> 1)) & 3) * 8;

  const int kg = t & 15, dg = t >> 4;
  const int vc   = (kg >> 3) * 32;
  const int vq   = kg & 3;
  const int vsub = ((kg >> 2) & 1) * 4;

  const ushort* gK = Kb + (size_t)krow * 64 + kac * 8;
  const ushort* gV = Vb + (size_t)(kg * 4) * 64 + dg * 4;

  f16x8 kr0, kr1;
  ushort4 vr[4];
  kr0 = *(const f16x8*)(gK);
  kr1 = *(const f16x8*)(gK + 32);
#pragma unroll
  for (int i = 0; i < 4; ++i) vr[i] = *(const ushort4*)(gV + (size_t)i * 64);

  for (int kt = 0; kt < 32; ++kt) {
    __syncthreads();
    *(f16x8*)&Ks[kl]      = kr0;
    *(f16x8*)&Ks[kl + 32] = kr1;
    {
      const uint* w0 = (const uint*)&vr[0];
      const uint* w1 = (const uint*)&vr[1];
      const uint* w2 = (const uint*)&vr[2];
      const uint* w3 = (const uint*)&vr[3];
#pragma unroll
      for (int j = 0; j < 4; ++j) {
        const int  wd  = j >> 1;
        const uint sel = (j & 1) ? 0x07060302u : 0x05040100u;
        const uint lo  = __builtin_amdgcn_perm(w1[wd], w0[wd], sel);
        const uint hi  = __builtin_amdgcn_perm(w3[wd], w2[wd], sel);
        const int row  = dg * 4 + j;
        const int slot = (vq + (row >> 1)) & 3;
        *(uint2*)&Vt[row * 64 + vc + slot * 8 + vsub] = make_uint2(lo, hi);
      }
    }
    __syncthreads();

    if (kt < 31) {
      const size_t adv = (size_t)(kt + 1) * 64 * 64;
      kr0 = *(const f16x8*)(gK + adv);
      kr1 = *(const f16x8*)(gK + adv + 32);
#pragma unroll
      for (int i = 0; i < 4; ++i) vr[i] = *(const ushort4*)(gV + adv + (size_t)i * 64);
    }

    // ---- QK^T, both q-halves share each K fragment ----
    f32x4 st[2][2][4];  // [qh][mt][j]
#pragma unroll
    for (int j = 0; j < 4; ++j) {
      const f16x8 ak0 = *(const f16x8*)&Ks[(j * 16 + c16) * 64 + fslot];
      st[0][0][j] = __builtin_amdgcn_mfma_f32_16x16x32_f16(ak0, aq[0][0][0], kZ, 0, 0, 0);
      st[0][1][j] = __builtin_amdgcn_mfma_f32_16x16x32_f16(ak0, aq[0][1][0], kZ, 0, 0, 0);
      st[1][0][j] = __builtin_amdgcn_mfma_f32_16x16x32_f16(ak0, aq[1][0][0], kZ, 0, 0, 0);
      st[1][1][j] = __builtin_amdgcn_mfma_f32_16x16x32_f16(ak0, aq[1][1][0], kZ, 0, 0, 0);
    }
#pragma unroll
    for (int j = 0; j < 4; ++j) {
      const f16x8 ak1 = *(const f16x8*)&Ks[(j * 16 + c16) * 64 + 32 + fslot];
      st[0][0][j] = __builtin_amdgcn_mfma_f32_16x16x32_f16(ak1, aq[0][0][1], st[0][0][j], 0, 0, 0);
      st[0][1][j] = __builtin_amdgcn_mfma_f32_16x16x32_f16(ak1, aq[0][1][1], st[0][1][j], 0, 0, 0);
      st[1][0][j] = __builtin_amdgcn_mfma_f32_16x16x32_f16(ak1, aq[1][0][1], st[1][0][j], 0, 0, 0);
      st[1][1][j] = __builtin_amdgcn_mfma_f32_16x16x32_f16(ak1, aq[1][1][1], st[1][1][j], 0, 0, 0);
    }

    // ---- softmax exp2 + fp16 pack, both halves ----
    US8 pf[2][2][2];  // [qh][mt][c2]
#pragma unroll
    for (int qh = 0; qh < 2; ++qh)
#pragma unroll
      for (int mt = 0; mt < 2; ++mt)
#pragma unroll
        for (int c2 = 0; c2 < 2; ++c2)
#pragma unroll
          for (int w = 0; w < 4; ++w) {
            const int jj = c2 * 2 + (w >> 1);
            const int r0 = (w & 1) * 2;
            const float pe = __builtin_amdgcn_exp2f(st[qh][mt][jj][r0]);
            const float po = __builtin_amdgcn_exp2f(st[qh][mt][jj][r0 + 1]);
            const auto pk = __builtin_amdgcn_cvt_pkrtz(pe, po);
            pf[qh][mt][c2].w[w] = __builtin_bit_cast(uint, pk);
          }

    // ---- PV + row-sum, both q-halves share each V fragment ----
#pragma unroll
    for (int c2 = 0; c2 < 2; ++c2) {
      lacc[0][0] = __builtin_amdgcn_mfma_f32_16x16x32_f16(pf[0][0][c2].v, ones, lacc[0][0], 0, 0, 0);
      lacc[0][1] = __builtin_amdgcn_mfma_f32_16x16x32_f16(pf[0][1][c2].v, ones, lacc[0][1], 0, 0, 0);
      lacc[1][0] = __builtin_amdgcn_mfma_f32_16x16x32_f16(pf[1][0][c2].v, ones, lacc[1][0], 0, 0, 0);
      lacc[1][1] = __builtin_amdgcn_mfma_f32_16x16x32_f16(pf[1][1][c2].v, ones, lacc[1][1], 0, 0, 0);
#pragma unroll
      for (int j = 0; j < 4; ++j) {
        const f16x8 bv = *(const f16x8*)&Vt[(j * 16 + c16) * 64 + c2 * 32 + fslot];
        ctx[0][0][j] = __builtin_amdgcn_mfma_f32_16x16x32_f16(pf[0][0][c2].v, bv, ctx[0][0][j], 0, 0, 0);
        ctx[0][1][j] = __builtin_amdgcn_mfma_f32_16x16x32_f16(pf[0][1][c2].v, bv, ctx[0][1][j], 0, 0, 0);
        ctx[1][0][j] = __builtin_amdgcn_mfma_f32_16x16x32_f16(pf[1][0][c2].v, bv, ctx[1][0][j], 0, 0, 0);
        ctx[1][1][j] = __builtin_amdgcn_mfma_f32_16x16x32_f16(pf[1][1][c2].v, bv, ctx[1][1][j], 0, 0, 0);
      }
    }
  }

#pragma unroll
  for (int qh = 0; qh < 2; ++qh)
#pragma unroll
    for (int mt = 0; mt < 2; ++mt) {
#pragma unroll
      for (int r = 0; r < 4; ++r) {
        const float inv = 1.f / lacc[qh][mt][r];
        const int srow  = qt * 256 + wave * 64 + qh * 32 + mt * 16 + quad * 4 + r;
        const size_t rb = ((size_t)(bb * Sc + srow)) * 1024 + hh * 64;
#pragma unroll
        for (int j = 0; j < 4; ++j)
          CTX[rb + j * 16 + c16] = f2h(ctx[qh][mt][j][r] * inv);
      }
    }
}

extern "C" void kernel_launch(void* const* d_in, const int* in_sizes, int n_in,
                              void* d_out, int out_size, void* d_ws, size_t ws_size,
                              hipStream_t stream) {
  (void)in_sizes; (void)n_in; (void)out_size; (void)ws_size;
  const float* x  = (const float*)d_in[0];
  const float* Wq = (const float*)d_in[1];
  const float* bq = (const float*)d_in[2];
  const float* Wk = (const float*)d_in[3];
  const float* bk = (const float*)d_in[4];
  const float* Wv = (const float*)d_in[5];
  const float* bv = (const float*)d_in[6];
  const float* Wo = (const float*)d_in[7];
  const float* bo = (const float*)d_in[8];

  const size_t MB = 1024 * 1024;
  char* w    = (char*)d_ws;
  ushort* Qw  = (ushort*)(w + 0 * MB);   // [B,H,S,HD] fp16 (pre-scaled by EC)
  ushort* Kw  = (ushort*)(w + 8 * MB);
  ushort* Vw  = (ushort*)(w + 16 * MB);
  ushort* Cw  = (ushort*)(w + 24 * MB);  // ctx [M,1024] fp16
  ushort* Xh  = (ushort*)(w + 32 * MB);  // x fp16 [M,1024]
  ushort* WT  = (ushort*)(w + 40 * MB);  // 4 x 2 MB fp16 W^T planes
  ushort* Whq = WT + 0 * 1048576;
  ushort* Whk = WT + 1 * 1048576;
  ushort* Whv = WT + 2 * 1048576;
  ushort* Who = WT + 3 * 1048576;

  const dim3 blk(256);

  SplitP sp;
  sp.W[0] = Wq; sp.W[1] = Wk; sp.W[2] = Wv; sp.W[3] = Wo;
  sp.Th[0] = Whq; sp.Th[1] = Whk; sp.Th[2] = Whv; sp.Th[3] = Who;
  prep_kernel<<<dim3(5120), blk, 0, stream>>>(x, Xh, sp);

  GemmP pq;
  pq.Bh[0] = Whq; pq.Bh[1] = Whk; pq.Bh[2] = Whv;
  pq.bias[0] = bq; pq.bias[1] = bk; pq.bias[2] = bv;
  pq.Out[0] = Qw; pq.Out[1] = Kw; pq.Out[2] = Vw;
  gemm_f16<true><<<dim3(Mc / 128, Dc / 128, 3), blk, 0, stream>>>(Xh, pq);

  attn_mfma3<<<dim3(256), blk, 0, stream>>>(Qw, Kw, Vw, Cw);

  GemmP po;
  po.Bh[0] = po.Bh[1] = po.Bh[2] = Who;
  po.bias[0] = po.bias[1] = po.bias[2] = bo;
  po.Out[0] = po.Out[1] = po.Out[2] = d_out;
  gemm_f16<false><<<dim3(Mc / 128, Dc / 128, 1), blk, 0, stream>>>(Cw, po);
}

// Round 9
// 204.043 us; speedup vs baseline: 1.0608x; 1.0608x over previous
//
#include <hip/hip_runtime.h>
#include <hip/hip_bf16.h>

typedef __attribute__((ext_vector_type(8))) _Float16 f16x8;  // 8 fp16 (4 VGPR)
typedef __attribute__((ext_vector_type(4))) float f32x4;     // MFMA C/D frag

constexpr int Sc  = 2048;
constexpr int Dc  = 1024;
constexpr int Hc  = 16;
constexpr int HDc = 64;
constexpr int Mc  = 4096;  // B*S

constexpr float ECs = 0.18033688011112042f;  // log2(e)/8, folded into Q

__device__ __forceinline__ ushort f2h(float f) {
  return __builtin_bit_cast(ushort, (_Float16)f);
}

union US8 {
  ushort u[8];
  uint   w[4];
  f16x8  v;
};

// ---------------------------------------------------------------------------
// prep: merged split_x (blocks 0..4095) + split_wt (blocks 4096..5119).
// ---------------------------------------------------------------------------
struct SplitP {
  const float* W[4];
  ushort*      Th[4];
};

__global__ __launch_bounds__(256) void prep_kernel(
    const float* __restrict__ X, ushort* __restrict__ Xh, SplitP p) {
  __shared__ float T[64][69];
  const int wid = blockIdx.x;
  const int t   = threadIdx.x;
  if (wid < 4096) {
    const int i    = wid * 256 + t;
    const float4 v = ((const float4*)X)[i];
    ushort4 h;
    h.x = f2h(v.x);
    h.y = f2h(v.y);
    h.z = f2h(v.z);
    h.w = f2h(v.w);
    ((ushort4*)Xh)[i] = h;
    return;
  }
  const int w2 = wid - 4096;
  const int z  = w2 >> 8;
  const int by = (w2 >> 4) & 15;
  const int bx = w2 & 15;
  const float* W = p.W[z];
  const int c  = (t & 15) * 4;
  const int r  = t >> 4;
  const int n0 = bx * 64, k0 = by * 64;
#pragma unroll
  for (int pp = 0; pp < 4; ++pp) {
    const int k    = r + pp * 16;
    const float4 v = *(const float4*)(W + (size_t)(k0 + k) * 1024 + n0 + c);
    T[k][c + 0] = v.x;
    T[k][c + 1] = v.y;
    T[k][c + 2] = v.z;
    T[k][c + 3] = v.w;
  }
  __syncthreads();
#pragma unroll
  for (int pp = 0; pp < 4; ++pp) {
    const int n = r + pp * 16;
    ushort4 h;
    h.x = f2h(T[c + 0][n]);
    h.y = f2h(T[c + 1][n]);
    h.z = f2h(T[c + 2][n]);
    h.w = f2h(T[c + 3][n]);
    *(ushort4*)(p.Th[z] + (size_t)(n0 + n) * 1024 + k0 + c) = h;
  }
}

// ---------------------------------------------------------------------------
// fp16 MFMA GEMM with register-prefetch pipeline + XOR-swizzled LDS.
// ---------------------------------------------------------------------------
struct GemmP {
  const ushort* Bh[3];
  const float*  bias[3];
  void*         Out[3];
};

template <bool QKV>
__global__ __launch_bounds__(256) void gemm_f16(
    const ushort* __restrict__ A, GemmP p) {
  __shared__ __align__(16) ushort As[128 * 32];
  __shared__ __align__(16) ushort Bs[128 * 32];

  const int t  = threadIdx.x;
  const int z  = blockIdx.z;
  const int m0 = blockIdx.x * 128, n0 = blockIdx.y * 128;
  const ushort* Bh  = p.Bh[z];
  const float* bias = p.bias[z];

  const int lane = t & 63, wave = t >> 6;
  const int wm = (wave & 1) * 64, wn = (wave >> 1) * 64;

  f32x4 acc[4][4];
#pragma unroll
  for (int i = 0; i < 4; ++i)
#pragma unroll
    for (int j = 0; j < 4; ++j) acc[i][j] = (f32x4){0.f, 0.f, 0.f, 0.f};

  const int am = t >> 2;
  const int ac = t & 3;
  const ushort* gA  = A  + (size_t)(m0 + am) * 1024 + ac * 8;
  const ushort* gBh = Bh + (size_t)(n0 + am) * 1024 + ac * 8;
  const int sw = ((ac + (am >> 1)) & 3) * 8;
  const int l0 = am * 32 + sw, l1 = (am + 64) * 32 + sw;

  const int fr  = lane & 15;
  const int fkb = (((lane >> 4) + (fr >> 1)) & 3) * 16;

  f16x8 rA0, rA1, rH0, rH1;
  rA0 = *(const f16x8*)(gA);
  rA1 = *(const f16x8*)(gA + 64 * 1024);
  rH0 = *(const f16x8*)(gBh);
  rH1 = *(const f16x8*)(gBh + 64 * 1024);

  for (int k0 = 0; k0 < 1024; k0 += 32) {
    __syncthreads();
    *(f16x8*)&As[l0] = rA0;
    *(f16x8*)&As[l1] = rA1;
    *(f16x8*)&Bs[l0] = rH0;
    *(f16x8*)&Bs[l1] = rH1;
    __syncthreads();

    if (k0 + 32 < 1024) {
      const int kn = k0 + 32;
      rA0 = *(const f16x8*)(gA + kn);
      rA1 = *(const f16x8*)(gA + kn + 64 * 1024);
      rH0 = *(const f16x8*)(gBh + kn);
      rH1 = *(const f16x8*)(gBh + kn + 64 * 1024);
    }

    f16x8 a[4], b_h[4];
#pragma unroll
    for (int i = 0; i < 4; ++i) {
      const int ra = (wm + i * 16 + fr) * 64 + fkb;
      const int rb = (wn + i * 16 + fr) * 64 + fkb;
      a[i]   = *(const f16x8*)((const char*)As + ra);
      b_h[i] = *(const f16x8*)((const char*)Bs + rb);
    }
#pragma unroll
    for (int i = 0; i < 4; ++i)
#pragma unroll
      for (int j = 0; j < 4; ++j)
        acc[i][j] = __builtin_amdgcn_mfma_f32_16x16x32_f16(a[i], b_h[j], acc[i][j], 0, 0, 0);
  }

  const float osc = (QKV && z == 0) ? ECs : 1.0f;
  const int cr = (lane >> 4) * 4;
  const int cc = lane & 15;
#pragma unroll
  for (int j = 0; j < 4; ++j) {
    const int n    = n0 + wn + j * 16 + cc;
    const float bv = bias[n];
#pragma unroll
    for (int i = 0; i < 4; ++i) {
      const int mb = m0 + wm + i * 16 + cr;
#pragma unroll
      for (int r = 0; r < 4; ++r) {
        const int m   = mb + r;
        const float v = (acc[i][j][r] + bv) * osc;
        if (QKV) {
          const int b = m >> 11, s = m & 2047, h = n >> 6, hd = n & 63;
          ((ushort*)p.Out[z])[(((size_t)(b * Hc + h) * Sc + s) << 6) + hd] = f2h(v);
        } else {
          ((float*)p.Out[z])[(size_t)m * 1024 + n] = v;
        }
      }
    }
  }
}

// ---------------------------------------------------------------------------
// MFMA flash attention — 512-thread block hybrid (r5 TLP + r7 amortization).
// Evidence: r5 (2 waves/SIMD) 56.4us; r7 (amortized staging, 1 wave/SIMD)
// 52.7us; r8 (ILP fusion) regressed 70us -> single-wave ILP can't replace
// TLP. This round: 8 waves x 32 q-rows = QBLOCK 256 per block, 256 blocks
// = 1 block/CU = 2 waves/SIMD, staging one K/V tile per 256 q-rows (half of
// r5's per-CU staging). Role split: waves 0-3 stage K, waves 4-7 stage V
// (staging critical path halves). Per-wave compute = r5's proven pipeline
// verbatim (st[2][4], pf[2][2], setprio). Numerics per q-row identical.
// ---------------------------------------------------------------------------
__global__ __launch_bounds__(512, 1) void attn_mfma3(
    const ushort* __restrict__ Q, const ushort* __restrict__ K,
    const ushort* __restrict__ V, ushort* __restrict__ CTX) {
  __shared__ __align__(16) ushort Ks[64 * 64];
  __shared__ __align__(16) ushort Vt[64 * 64];  // [d][l(k) swizzled]

  const int t    = threadIdx.x;
  const int lane = t & 63, wave = t >> 6;  // wave 0..7
  const int c16 = lane & 15, quad = lane >> 4;
  const int wg = blockIdx.x;
  const int bh = wg & 31, qt = wg >> 5;  // bh fast: xcd = bh%8 (L2 affinity)
  const int bb = bh >> 4, hh = bh & 15;

  const ushort* Qb = Q + (size_t)bh * Sc * HDc + (size_t)qt * 256 * HDc;
  const ushort* Kb = K + (size_t)bh * Sc * HDc;
  const ushort* Vb = V + (size_t)bh * Sc * HDc;

  // 32 q-rows per wave: rows qt*256 + wave*32 + ...
  f16x8 aq[2][2];
#pragma unroll
  for (int mt = 0; mt < 2; ++mt)
#pragma unroll
    for (int c = 0; c < 2; ++c)
      aq[mt][c] = *(const f16x8*)(Qb +
          (size_t)(wave * 32 + mt * 16 + c16) * 64 + c * 32 + quad * 8);

  US8 ones_u;
#pragma unroll
  for (int e = 0; e < 8; ++e) ones_u.u[e] = 0x3C00;  // fp16 1.0
  const f16x8 ones = ones_u.v;
  const f32x4 kZ = (f32x4){0.f, 0.f, 0.f, 0.f};  // hoisted MFMA C=0

  f32x4 ctx[2][4], lacc[2];
#pragma unroll
  for (int mt = 0; mt < 2; ++mt) {
    lacc[mt] = (f32x4){0.f, 0.f, 0.f, 0.f};
#pragma unroll
    for (int j = 0; j < 4; ++j) ctx[mt][j] = (f32x4){0.f, 0.f, 0.f, 0.f};
  }

  const int fslot = ((quad + (c16 >> 1)) & 3) * 8;

  // staging role: waves 0-3 stage K, waves 4-7 stage V (ts = role-local tid)
  const bool isK = (t < 256);
  const int ts  = isK ? t : (t - 256);

  // K path (ts 0..255): row krow, logical chunk kac of both halves
  const int krow = ts >> 2, kac = ts & 3;
  const int kl = krow * 64 + ((kac + (krow >> 1)) & 3) * 8;

  // V path (ts 0..255): covers logical k = kg*4..+3, d = dg*4..+3
  const int kg = ts & 15, dg = ts >> 4;
  const int vc   = (kg >> 3) * 32;
  const int vq   = kg & 3;
  const int vsub = ((kg >> 2) & 1) * 4;

  const ushort* gK = Kb + (size_t)krow * 64 + kac * 8;
  const ushort* gV = Vb + (size_t)(kg * 4) * 64 + dg * 4;

  f16x8 kr0, kr1;
  ushort4 vr[4];
  if (isK) {
    kr0 = *(const f16x8*)(gK);
    kr1 = *(const f16x8*)(gK + 32);
  } else {
#pragma unroll
    for (int i = 0; i < 4; ++i) vr[i] = *(const ushort4*)(gV + (size_t)i * 64);
  }

  for (int kt = 0; kt < 32; ++kt) {
    __syncthreads();
    if (isK) {
      *(f16x8*)&Ks[kl]      = kr0;
      *(f16x8*)&Ks[kl + 32] = kr1;
    } else {
      const uint* w0 = (const uint*)&vr[0];
      const uint* w1 = (const uint*)&vr[1];
      const uint* w2 = (const uint*)&vr[2];
      const uint* w3 = (const uint*)&vr[3];
#pragma unroll
      for (int j = 0; j < 4; ++j) {
        const int  wd  = j >> 1;
        const uint sel = (j & 1) ? 0x07060302u : 0x05040100u;
        const uint lo  = __builtin_amdgcn_perm(w1[wd], w0[wd], sel);
        const uint hi  = __builtin_amdgcn_perm(w3[wd], w2[wd], sel);
        const int row  = dg * 4 + j;
        const int slot = (vq + (row >> 1)) & 3;
        *(uint2*)&Vt[row * 64 + vc + slot * 8 + vsub] = make_uint2(lo, hi);
      }
    }
    __syncthreads();

    if (kt < 31) {
      const size_t adv = (size_t)(kt + 1) * 64 * 64;
      if (isK) {
        kr0 = *(const f16x8*)(gK + adv);
        kr1 = *(const f16x8*)(gK + adv + 32);
      } else {
#pragma unroll
        for (int i = 0; i < 4; ++i) vr[i] = *(const ushort4*)(gV + adv + (size_t)i * 64);
      }
    }

    // QK^T: c=0 uses the hoisted zero C operand
    f32x4 st[2][4];
    __builtin_amdgcn_s_setprio(1);
#pragma unroll
    for (int j = 0; j < 4; ++j) {
      const f16x8 ak0 = *(const f16x8*)&Ks[(j * 16 + c16) * 64 + fslot];
      st[0][j] = __builtin_amdgcn_mfma_f32_16x16x32_f16(ak0, aq[0][0], kZ, 0, 0, 0);
      st[1][j] = __builtin_amdgcn_mfma_f32_16x16x32_f16(ak0, aq[1][0], kZ, 0, 0, 0);
    }
#pragma unroll
    for (int j = 0; j < 4; ++j) {
      const f16x8 ak1 = *(const f16x8*)&Ks[(j * 16 + c16) * 64 + 32 + fslot];
      st[0][j] = __builtin_amdgcn_mfma_f32_16x16x32_f16(ak1, aq[0][1], st[0][j], 0, 0, 0);
      st[1][j] = __builtin_amdgcn_mfma_f32_16x16x32_f16(ak1, aq[1][1], st[1][j], 0, 0, 0);
    }
    __builtin_amdgcn_s_setprio(0);

    US8 pf[2][2];
#pragma unroll
    for (int mt = 0; mt < 2; ++mt)
#pragma unroll
      for (int c2 = 0; c2 < 2; ++c2)
#pragma unroll
        for (int w = 0; w < 4; ++w) {
          const int jj = c2 * 2 + (w >> 1);
          const int r0 = (w & 1) * 2;
          const float pe = __builtin_amdgcn_exp2f(st[mt][jj][r0]);
          const float po = __builtin_amdgcn_exp2f(st[mt][jj][r0 + 1]);
          const auto pk = __builtin_amdgcn_cvt_pkrtz(pe, po);
          pf[mt][c2].w[w] = __builtin_bit_cast(uint, pk);
        }

    __builtin_amdgcn_s_setprio(1);
#pragma unroll
    for (int c2 = 0; c2 < 2; ++c2) {
      lacc[0] = __builtin_amdgcn_mfma_f32_16x16x32_f16(pf[0][c2].v, ones, lacc[0], 0, 0, 0);
      lacc[1] = __builtin_amdgcn_mfma_f32_16x16x32_f16(pf[1][c2].v, ones, lacc[1], 0, 0, 0);
#pragma unroll
      for (int j = 0; j < 4; ++j) {
        const f16x8 bv = *(const f16x8*)&Vt[(j * 16 + c16) * 64 + c2 * 32 + fslot];
        ctx[0][j] = __builtin_amdgcn_mfma_f32_16x16x32_f16(pf[0][c2].v, bv, ctx[0][j], 0, 0, 0);
        ctx[1][j] = __builtin_amdgcn_mfma_f32_16x16x32_f16(pf[1][c2].v, bv, ctx[1][j], 0, 0, 0);
      }
    }
    __builtin_amdgcn_s_setprio(0);
  }

#pragma unroll
  for (int mt = 0; mt < 2; ++mt) {
#pragma unroll
    for (int r = 0; r < 4; ++r) {
      const float inv = 1.f / lacc[mt][r];
      const int srow  = qt * 256 + wave * 32 + mt * 16 + quad * 4 + r;
      const size_t rb = ((size_t)(bb * Sc + srow)) * 1024 + hh * 64;
#pragma unroll
      for (int j = 0; j < 4; ++j)
        CTX[rb + j * 16 + c16] = f2h(ctx[mt][j][r] * inv);
    }
  }
}

extern "C" void kernel_launch(void* const* d_in, const int* in_sizes, int n_in,
                              void* d_out, int out_size, void* d_ws, size_t ws_size,
                              hipStream_t stream) {
  (void)in_sizes; (void)n_in; (void)out_size; (void)ws_size;
  const float* x  = (const float*)d_in[0];
  const float* Wq = (const float*)d_in[1];
  const float* bq = (const float*)d_in[2];
  const float* Wk = (const float*)d_in[3];
  const float* bk = (const float*)d_in[4];
  const float* Wv = (const float*)d_in[5];
  const float* bv = (const float*)d_in[6];
  const float* Wo = (const float*)d_in[7];
  const float* bo = (const float*)d_in[8];

  const size_t MB = 1024 * 1024;
  char* w    = (char*)d_ws;
  ushort* Qw  = (ushort*)(w + 0 * MB);   // [B,H,S,HD] fp16 (pre-scaled by EC)
  ushort* Kw  = (ushort*)(w + 8 * MB);
  ushort* Vw  = (ushort*)(w + 16 * MB);
  ushort* Cw  = (ushort*)(w + 24 * MB);  // ctx [M,1024] fp16
  ushort* Xh  = (ushort*)(w + 32 * MB);  // x fp16 [M,1024]
  ushort* WT  = (ushort*)(w + 40 * MB);  // 4 x 2 MB fp16 W^T planes
  ushort* Whq = WT + 0 * 1048576;
  ushort* Whk = WT + 1 * 1048576;
  ushort* Whv = WT + 2 * 1048576;
  ushort* Who = WT + 3 * 1048576;

  const dim3 blk(256);

  SplitP sp;
  sp.W[0] = Wq; sp.W[1] = Wk; sp.W[2] = Wv; sp.W[3] = Wo;
  sp.Th[0] = Whq; sp.Th[1] = Whk; sp.Th[2] = Whv; sp.Th[3] = Who;
  prep_kernel<<<dim3(5120), blk, 0, stream>>>(x, Xh, sp);

  GemmP pq;
  pq.Bh[0] = Whq; pq.Bh[1] = Whk; pq.Bh[2] = Whv;
  pq.bias[0] = bq; pq.bias[1] = bk; pq.bias[2] = bv;
  pq.Out[0] = Qw; pq.Out[1] = Kw; pq.Out[2] = Vw;
  gemm_f16<true><<<dim3(Mc / 128, Dc / 128, 3), blk, 0, stream>>>(Xh, pq);

  attn_mfma3<<<dim3(256), dim3(512), 0, stream>>>(Qw, Kw, Vw, Cw);

  GemmP po;
  po.Bh[0] = po.Bh[1] = po.Bh[2] = Who;
  po.bias[0] = po.bias[1] = po.bias[2] = bo;
  po.Out[0] = po.Out[1] = po.Out[2] = d_out;
  gemm_f16<false><<<dim3(Mc / 128, Dc / 128, 1), blk, 0, stream>>>(Cw, po);
}

// Round 10
// 185.006 us; speedup vs baseline: 1.1700x; 1.1029x over previous
//
#include <hip/hip_runtime.h>
#include <hip/hip_bf16.h>

typedef __attribute__((ext_vector_type(8))) _Float16 f16x8;  // 8 fp16 (4 VGPR)
typedef __attribute__((ext_vector_type(4))) float f32x4;     // MFMA C/D frag

constexpr int Sc  = 2048;
constexpr int Dc  = 1024;
constexpr int Hc  = 16;
constexpr int HDc = 64;
constexpr int Mc  = 4096;  // B*S

constexpr float ECs = 0.18033688011112042f;  // log2(e)/8, folded into Q

__device__ __forceinline__ ushort f2h(float f) {
  return __builtin_bit_cast(ushort, (_Float16)f);
}

union US8 {
  ushort u[8];
  uint   w[4];
  f16x8  v;
};

// ---------------------------------------------------------------------------
// prep: merged split_x (blocks 0..4095) + split_wt (blocks 4096..5119).
// ---------------------------------------------------------------------------
struct SplitP {
  const float* W[4];
  ushort*      Th[4];
};

__global__ __launch_bounds__(256) void prep_kernel(
    const float* __restrict__ X, ushort* __restrict__ Xh, SplitP p) {
  __shared__ float T[64][69];
  const int wid = blockIdx.x;
  const int t   = threadIdx.x;
  if (wid < 4096) {
    const int i    = wid * 256 + t;
    const float4 v = ((const float4*)X)[i];
    ushort4 h;
    h.x = f2h(v.x);
    h.y = f2h(v.y);
    h.z = f2h(v.z);
    h.w = f2h(v.w);
    ((ushort4*)Xh)[i] = h;
    return;
  }
  const int w2 = wid - 4096;
  const int z  = w2 >> 8;
  const int by = (w2 >> 4) & 15;
  const int bx = w2 & 15;
  const float* W = p.W[z];
  const int c  = (t & 15) * 4;
  const int r  = t >> 4;
  const int n0 = bx * 64, k0 = by * 64;
#pragma unroll
  for (int pp = 0; pp < 4; ++pp) {
    const int k    = r + pp * 16;
    const float4 v = *(const float4*)(W + (size_t)(k0 + k) * 1024 + n0 + c);
    T[k][c + 0] = v.x;
    T[k][c + 1] = v.y;
    T[k][c + 2] = v.z;
    T[k][c + 3] = v.w;
  }
  __syncthreads();
#pragma unroll
  for (int pp = 0; pp < 4; ++pp) {
    const int n = r + pp * 16;
    ushort4 h;
    h.x = f2h(T[c + 0][n]);
    h.y = f2h(T[c + 1][n]);
    h.z = f2h(T[c + 2][n]);
    h.w = f2h(T[c + 3][n]);
    *(ushort4*)(p.Th[z] + (size_t)(n0 + n) * 1024 + k0 + c) = h;
  }
}

// ---------------------------------------------------------------------------
// fp16 MFMA GEMM, BK=64 K-unroll (two 32-chunks per barrier pair).
// r2 halved MFMA/k-step (2-product -> 1) and per-step barrier overhead became
// dominant (ladder m90: 16-MFMA/step 128^2 structures sit ~334 TF). BK=64
// restores 32 MFMA per barrier pair at the same staging pattern: LDS 32 KB
// (2 sub-tiles x 8 KB x A,B), 16 k-steps. Accumulation order bit-identical
// (kk=0 then kk=1 = previous sequential chunk order).
// ---------------------------------------------------------------------------
struct GemmP {
  const ushort* Bh[3];
  const float*  bias[3];
  void*         Out[3];
};

template <bool QKV>
__global__ __launch_bounds__(256) void gemm_f16(
    const ushort* __restrict__ A, GemmP p) {
  __shared__ __align__(16) ushort As[2][128 * 32];
  __shared__ __align__(16) ushort Bs[2][128 * 32];

  const int t  = threadIdx.x;
  const int z  = blockIdx.z;
  const int m0 = blockIdx.x * 128, n0 = blockIdx.y * 128;
  const ushort* Bh  = p.Bh[z];
  const float* bias = p.bias[z];

  const int lane = t & 63, wave = t >> 6;
  const int wm = (wave & 1) * 64, wn = (wave >> 1) * 64;

  f32x4 acc[4][4];
#pragma unroll
  for (int i = 0; i < 4; ++i)
#pragma unroll
    for (int j = 0; j < 4; ++j) acc[i][j] = (f32x4){0.f, 0.f, 0.f, 0.f};

  const int am = t >> 2;
  const int ac = t & 3;
  const ushort* gA  = A  + (size_t)(m0 + am) * 1024 + ac * 8;
  const ushort* gBh = Bh + (size_t)(n0 + am) * 1024 + ac * 8;
  const int sw = ((ac + (am >> 1)) & 3) * 8;
  const int l0 = am * 32 + sw, l1 = (am + 64) * 32 + sw;

  const int fr  = lane & 15;
  const int fkb = (((lane >> 4) + (fr >> 1)) & 3) * 16;

  // preload k-tile 0: sub0 (k..k+31) and sub1 (k+32..k+63), rows am & am+64
  f16x8 rA0, rA1, rA2, rA3, rH0, rH1, rH2, rH3;
  rA0 = *(const f16x8*)(gA);
  rA1 = *(const f16x8*)(gA + 64 * 1024);
  rA2 = *(const f16x8*)(gA + 32);
  rA3 = *(const f16x8*)(gA + 32 + 64 * 1024);
  rH0 = *(const f16x8*)(gBh);
  rH1 = *(const f16x8*)(gBh + 64 * 1024);
  rH2 = *(const f16x8*)(gBh + 32);
  rH3 = *(const f16x8*)(gBh + 32 + 64 * 1024);

  for (int k0 = 0; k0 < 1024; k0 += 64) {
    __syncthreads();  // prev compute done reading LDS
    *(f16x8*)&As[0][l0] = rA0;
    *(f16x8*)&As[0][l1] = rA1;
    *(f16x8*)&As[1][l0] = rA2;
    *(f16x8*)&As[1][l1] = rA3;
    *(f16x8*)&Bs[0][l0] = rH0;
    *(f16x8*)&Bs[0][l1] = rH1;
    *(f16x8*)&Bs[1][l0] = rH2;
    *(f16x8*)&Bs[1][l1] = rH3;
    __syncthreads();

    // prefetch next 64-wide k-tile (overlaps the whole compute phase)
    if (k0 + 64 < 1024) {
      const int kn = k0 + 64;
      rA0 = *(const f16x8*)(gA + kn);
      rA1 = *(const f16x8*)(gA + kn + 64 * 1024);
      rA2 = *(const f16x8*)(gA + kn + 32);
      rA3 = *(const f16x8*)(gA + kn + 32 + 64 * 1024);
      rH0 = *(const f16x8*)(gBh + kn);
      rH1 = *(const f16x8*)(gBh + kn + 64 * 1024);
      rH2 = *(const f16x8*)(gBh + kn + 32);
      rH3 = *(const f16x8*)(gBh + kn + 32 + 64 * 1024);
    }

#pragma unroll
    for (int kk = 0; kk < 2; ++kk) {
      f16x8 a[4], b_h[4];
#pragma unroll
      for (int i = 0; i < 4; ++i) {
        const int ra = (wm + i * 16 + fr) * 64 + fkb;  // bytes within sub-tile
        const int rb = (wn + i * 16 + fr) * 64 + fkb;
        a[i]   = *(const f16x8*)((const char*)As[kk] + ra);
        b_h[i] = *(const f16x8*)((const char*)Bs[kk] + rb);
      }
#pragma unroll
      for (int i = 0; i < 4; ++i)
#pragma unroll
        for (int j = 0; j < 4; ++j)
          acc[i][j] = __builtin_amdgcn_mfma_f32_16x16x32_f16(a[i], b_h[j], acc[i][j], 0, 0, 0);
    }
  }

  const float osc = (QKV && z == 0) ? ECs : 1.0f;
  const int cr = (lane >> 4) * 4;
  const int cc = lane & 15;
#pragma unroll
  for (int j = 0; j < 4; ++j) {
    const int n    = n0 + wn + j * 16 + cc;
    const float bv = bias[n];
#pragma unroll
    for (int i = 0; i < 4; ++i) {
      const int mb = m0 + wm + i * 16 + cr;
#pragma unroll
      for (int r = 0; r < 4; ++r) {
        const int m   = mb + r;
        const float v = (acc[i][j][r] + bv) * osc;
        if (QKV) {
          const int b = m >> 11, s = m & 2047, h = n >> 6, hd = n & 63;
          ((ushort*)p.Out[z])[(((size_t)(b * Hc + h) * Sc + s) << 6) + hd] = f2h(v);
        } else {
          ((float*)p.Out[z])[(size_t)m * 1024 + n] = v;
        }
      }
    }
  }
}

// ---------------------------------------------------------------------------
// MFMA flash attention — r7 structure verbatim (measured 52.7 us, the best of
// 7 structural variants: r3 split-KV 62, r5 swizzle 56.4, r6 dbuf 57.3,
// r8 ILP-fusion 70, r9 512-thr 59.2). QBLOCK=256: each wave serves 64 q-rows
// as two sequential 32-row halves; 256 blocks, bh=wg&31 (XCD L2 affinity);
// single-buffer 2-barrier staging; setprio around MFMA clusters; hoisted
// zero-C QK init. ~662 TF effective = 77% of the GEMM-structure rate.
// ---------------------------------------------------------------------------
__global__ __launch_bounds__(256, 2) void attn_mfma3(
    const ushort* __restrict__ Q, const ushort* __restrict__ K,
    const ushort* __restrict__ V, ushort* __restrict__ CTX) {
  __shared__ __align__(16) ushort Ks[64 * 64];
  __shared__ __align__(16) ushort Vt[64 * 64];  // [d][l(k) swizzled]

  const int t    = threadIdx.x;
  const int lane = t & 63, wave = t >> 6;
  const int c16 = lane & 15, quad = lane >> 4;
  const int wg = blockIdx.x;
  const int bh = wg & 31, qt = wg >> 5;  // bh fast: xcd = bh%8 (L2 affinity)
  const int bb = bh >> 4, hh = bh & 15;

  const ushort* Qb = Q + (size_t)bh * Sc * HDc + (size_t)qt * 256 * HDc;
  const ushort* Kb = K + (size_t)bh * Sc * HDc;
  const ushort* Vb = V + (size_t)bh * Sc * HDc;

  // 64 q-rows per wave: [qh][mt][c]
  f16x8 aq[2][2][2];
#pragma unroll
  for (int qh = 0; qh < 2; ++qh)
#pragma unroll
    for (int mt = 0; mt < 2; ++mt)
#pragma unroll
      for (int c = 0; c < 2; ++c)
        aq[qh][mt][c] = *(const f16x8*)(Qb +
            (size_t)(wave * 64 + qh * 32 + mt * 16 + c16) * 64 + c * 32 + quad * 8);

  US8 ones_u;
#pragma unroll
  for (int e = 0; e < 8; ++e) ones_u.u[e] = 0x3C00;  // fp16 1.0
  const f16x8 ones = ones_u.v;
  const f32x4 kZ = (f32x4){0.f, 0.f, 0.f, 0.f};  // hoisted MFMA C=0

  f32x4 ctx[2][2][4], lacc[2][2];
#pragma unroll
  for (int qh = 0; qh < 2; ++qh)
#pragma unroll
    for (int mt = 0; mt < 2; ++mt) {
      lacc[qh][mt] = (f32x4){0.f, 0.f, 0.f, 0.f};
#pragma unroll
      for (int j = 0; j < 4; ++j) ctx[qh][mt][j] = (f32x4){0.f, 0.f, 0.f, 0.f};
    }

  const int fslot = ((quad + (c16 >> 1)) & 3) * 8;

  const int krow = t >> 2, kac = t & 3;
  const int kl = krow * 64 + ((kac + (krow >> 1)) & 3) * 8;

  const int kg = t & 15, dg = t >> 4;
  const int vc   = (kg >> 3) * 32;
  const int vq   = kg & 3;
  const int vsub = ((kg >> 2) & 1) * 4;

  const ushort* gK = Kb + (size_t)krow * 64 + kac * 8;
  const ushort* gV = Vb + (size_t)(kg * 4) * 64 + dg * 4;

  f16x8 kr0, kr1;
  ushort4 vr[4];
  kr0 = *(const f16x8*)(gK);
  kr1 = *(const f16x8*)(gK + 32);
#pragma unroll
  for (int i = 0; i < 4; ++i) vr[i] = *(const ushort4*)(gV + (size_t)i * 64);

  for (int kt = 0; kt < 32; ++kt) {
    __syncthreads();
    *(f16x8*)&Ks[kl]      = kr0;
    *(f16x8*)&Ks[kl + 32] = kr1;
    {
      const uint* w0 = (const uint*)&vr[0];
      const uint* w1 = (const uint*)&vr[1];
      const uint* w2 = (const uint*)&vr[2];
      const uint* w3 = (const uint*)&vr[3];
#pragma unroll
      for (int j = 0; j < 4; ++j) {
        const int  wd  = j >> 1;
        const uint sel = (j & 1) ? 0x07060302u : 0x05040100u;
        const uint lo  = __builtin_amdgcn_perm(w1[wd], w0[wd], sel);
        const uint hi  = __builtin_amdgcn_perm(w3[wd], w2[wd], sel);
        const int row  = dg * 4 + j;
        const int slot = (vq + (row >> 1)) & 3;
        *(uint2*)&Vt[row * 64 + vc + slot * 8 + vsub] = make_uint2(lo, hi);
      }
    }
    __syncthreads();

    if (kt < 31) {
      const size_t adv = (size_t)(kt + 1) * 64 * 64;
      kr0 = *(const f16x8*)(gK + adv);
      kr1 = *(const f16x8*)(gK + adv + 32);
#pragma unroll
      for (int i = 0; i < 4; ++i) vr[i] = *(const ushort4*)(gV + adv + (size_t)i * 64);
    }

#pragma unroll
    for (int qh = 0; qh < 2; ++qh) {
      // QK^T for this q-half (c=0 with hoisted zero C)
      f32x4 st[2][4];
      __builtin_amdgcn_s_setprio(1);
#pragma unroll
      for (int j = 0; j < 4; ++j) {
        const f16x8 ak0 = *(const f16x8*)&Ks[(j * 16 + c16) * 64 + fslot];
        st[0][j] = __builtin_amdgcn_mfma_f32_16x16x32_f16(ak0, aq[qh][0][0], kZ, 0, 0, 0);
        st[1][j] = __builtin_amdgcn_mfma_f32_16x16x32_f16(ak0, aq[qh][1][0], kZ, 0, 0, 0);
      }
#pragma unroll
      for (int j = 0; j < 4; ++j) {
        const f16x8 ak1 = *(const f16x8*)&Ks[(j * 16 + c16) * 64 + 32 + fslot];
        st[0][j] = __builtin_amdgcn_mfma_f32_16x16x32_f16(ak1, aq[qh][0][1], st[0][j], 0, 0, 0);
        st[1][j] = __builtin_amdgcn_mfma_f32_16x16x32_f16(ak1, aq[qh][1][1], st[1][j], 0, 0, 0);
      }
      __builtin_amdgcn_s_setprio(0);

      US8 pf[2][2];
#pragma unroll
      for (int mt = 0; mt < 2; ++mt)
#pragma unroll
        for (int c2 = 0; c2 < 2; ++c2)
#pragma unroll
          for (int w = 0; w < 4; ++w) {
            const int jj = c2 * 2 + (w >> 1);
            const int r0 = (w & 1) * 2;
            const float pe = __builtin_amdgcn_exp2f(st[mt][jj][r0]);
            const float po = __builtin_amdgcn_exp2f(st[mt][jj][r0 + 1]);
            const auto pk = __builtin_amdgcn_cvt_pkrtz(pe, po);
            pf[mt][c2].w[w] = __builtin_bit_cast(uint, pk);
          }

      __builtin_amdgcn_s_setprio(1);
#pragma unroll
      for (int c2 = 0; c2 < 2; ++c2) {
        lacc[qh][0] = __builtin_amdgcn_mfma_f32_16x16x32_f16(pf[0][c2].v, ones, lacc[qh][0], 0, 0, 0);
        lacc[qh][1] = __builtin_amdgcn_mfma_f32_16x16x32_f16(pf[1][c2].v, ones, lacc[qh][1], 0, 0, 0);
#pragma unroll
        for (int j = 0; j < 4; ++j) {
          const f16x8 bv = *(const f16x8*)&Vt[(j * 16 + c16) * 64 + c2 * 32 + fslot];
          ctx[qh][0][j] = __builtin_amdgcn_mfma_f32_16x16x32_f16(pf[0][c2].v, bv, ctx[qh][0][j], 0, 0, 0);
          ctx[qh][1][j] = __builtin_amdgcn_mfma_f32_16x16x32_f16(pf[1][c2].v, bv, ctx[qh][1][j], 0, 0, 0);
        }
      }
      __builtin_amdgcn_s_setprio(0);
    }
  }

#pragma unroll
  for (int qh = 0; qh < 2; ++qh)
#pragma unroll
    for (int mt = 0; mt < 2; ++mt) {
#pragma unroll
      for (int r = 0; r < 4; ++r) {
        const float inv = 1.f / lacc[qh][mt][r];
        const int srow  = qt * 256 + wave * 64 + qh * 32 + mt * 16 + quad * 4 + r;
        const size_t rb = ((size_t)(bb * Sc + srow)) * 1024 + hh * 64;
#pragma unroll
        for (int j = 0; j < 4; ++j)
          CTX[rb + j * 16 + c16] = f2h(ctx[qh][mt][j][r] * inv);
      }
    }
}

extern "C" void kernel_launch(void* const* d_in, const int* in_sizes, int n_in,
                              void* d_out, int out_size, void* d_ws, size_t ws_size,
                              hipStream_t stream) {
  (void)in_sizes; (void)n_in; (void)out_size; (void)ws_size;
  const float* x  = (const float*)d_in[0];
  const float* Wq = (const float*)d_in[1];
  const float* bq = (const float*)d_in[2];
  const float* Wk = (const float*)d_in[3];
  const float* bk = (const float*)d_in[4];
  const float* Wv = (const float*)d_in[5];
  const float* bv = (const float*)d_in[6];
  const float* Wo = (const float*)d_in[7];
  const float* bo = (const float*)d_in[8];

  const size_t MB = 1024 * 1024;
  char* w    = (char*)d_ws;
  ushort* Qw  = (ushort*)(w + 0 * MB);   // [B,H,S,HD] fp16 (pre-scaled by EC)
  ushort* Kw  = (ushort*)(w + 8 * MB);
  ushort* Vw  = (ushort*)(w + 16 * MB);
  ushort* Cw  = (ushort*)(w + 24 * MB);  // ctx [M,1024] fp16
  ushort* Xh  = (ushort*)(w + 32 * MB);  // x fp16 [M,1024]
  ushort* WT  = (ushort*)(w + 40 * MB);  // 4 x 2 MB fp16 W^T planes
  ushort* Whq = WT + 0 * 1048576;
  ushort* Whk = WT + 1 * 1048576;
  ushort* Whv = WT + 2 * 1048576;
  ushort* Who = WT + 3 * 1048576;

  const dim3 blk(256);

  SplitP sp;
  sp.W[0] = Wq; sp.W[1] = Wk; sp.W[2] = Wv; sp.W[3] = Wo;
  sp.Th[0] = Whq; sp.Th[1] = Whk; sp.Th[2] = Whv; sp.Th[3] = Who;
  prep_kernel<<<dim3(5120), blk, 0, stream>>>(x, Xh, sp);

  GemmP pq;
  pq.Bh[0] = Whq; pq.Bh[1] = Whk; pq.Bh[2] = Whv;
  pq.bias[0] = bq; pq.bias[1] = bk; pq.bias[2] = bv;
  pq.Out[0] = Qw; pq.Out[1] = Kw; pq.Out[2] = Vw;
  gemm_f16<true><<<dim3(Mc / 128, Dc / 128, 3), blk, 0, stream>>>(Xh, pq);

  attn_mfma3<<<dim3(256), blk, 0, stream>>>(Qw, Kw, Vw, Cw);

  GemmP po;
  po.Bh[0] = po.Bh[1] = po.Bh[2] = Who;
  po.bias[0] = po.bias[1] = po.bias[2] = bo;
  po.Out[0] = po.Out[1] = po.Out[2] = d_out;
  gemm_f16<false><<<dim3(Mc / 128, Dc / 128, 1), blk, 0, stream>>>(Cw, po);
}